// Round 10
// baseline (468.021 us; speedup 1.0000x reference)
//
#include <hip/hip_runtime.h>
#include <hip/hip_bf16.h>
#include <stdint.h>
#include <math.h>

#define BB 8
#define SS 8192
#define NN 16
#define DD 64
#define MM 64
#define TS 32    // s-rows per LDS tile
#define PAD 40   // row stride (bf16): 80 B; b128 writes/reads both hit all 32 banks

typedef __attribute__((ext_vector_type(8))) short bf16x8;
typedef __attribute__((ext_vector_type(4))) float f32x4;

__device__ __forceinline__ float feat(float x) {
    // elu(x) + 1 == x+1 (x>0), exp(x) (x<=0); feat(-inf) = 0 (masked rows)
    return x > 0.0f ? (x + 1.0f) : __expf(x);
}

__device__ __forceinline__ uint32_t cvt_pk_bf16(float lo, float hi) {
    uint32_t r;
    asm("v_cvt_pk_bf16_f32 %0, %1, %2" : "=v"(r) : "v"(lo), "v"(hi));
    return r;
}

// 4x4 cross-lane u32 transpose on the VALU pipe (not LDS).
__device__ __forceinline__ void xpose4(uint32_t& x0, uint32_t& x1,
                                       uint32_t& x2, uint32_t& x3) {
    asm("v_permlane32_swap_b32 %0, %1" : "+v"(x0), "+v"(x2));
    asm("v_permlane32_swap_b32 %0, %1" : "+v"(x1), "+v"(x3));
    asm("v_permlane16_swap_b32 %0, %1" : "+v"(x0), "+v"(x1));
    asm("v_permlane16_swap_b32 %0, %1" : "+v"(x2), "+v"(x3));
}

// Raw barrier (no vmcnt drain): global loads stay in flight across it.
#define SYNCW()                                        \
    do {                                               \
        __builtin_amdgcn_sched_barrier(0);             \
        asm volatile("s_waitcnt lgkmcnt(0)");          \
        __builtin_amdgcn_s_barrier();                  \
        __builtin_amdgcn_sched_barrier(0);             \
    } while (0)

struct Slot {
    float4 kq0, kq1, vq0, vq1;
};

__device__ __forceinline__ void load_tile(Slot& s, int ti, uint32_t bits,
                                          const float* kb, const float* vb,
                                          int sl, int c0) {
    const bool lv0 = !((bits >> (2 * ti)) & 1);
    const bool lv1 = !((bits >> (2 * ti + 1)) & 1);
    const float ninf = -INFINITY;
    s.kq0 = make_float4(ninf, ninf, ninf, ninf);
    s.kq1 = make_float4(ninf, ninf, ninf, ninf);
    s.vq0 = make_float4(0.f, 0.f, 0.f, 0.f);
    s.vq1 = make_float4(0.f, 0.f, 0.f, 0.f);
    const size_t s0 = (size_t)(ti * TS + sl);
    if (lv0) {
        s.kq0 = *reinterpret_cast<const float4*>(kb + s0 * (NN * DD) + c0);
        s.vq0 = *reinterpret_cast<const float4*>(vb + s0 * (NN * MM) + c0);
    }
    if (lv1) {
        s.kq1 = *reinterpret_cast<const float4*>(kb + (s0 + 1) * (NN * DD) + c0);
        s.vq1 = *reinterpret_cast<const float4*>(vb + (s0 + 1) * (NN * MM) + c0);
    }
}

__device__ __forceinline__ void stage_tile(const Slot& s, float* zacc,
                                           __hip_bfloat16 (*Kbuf)[PAD],
                                           __hip_bfloat16 (*Vbuf)[PAD],
                                           int c0, int q, int woct) {
    const float sk0[4] = {s.kq0.x, s.kq0.y, s.kq0.z, s.kq0.w};
    const float sk1[4] = {s.kq1.x, s.kq1.y, s.kq1.z, s.kq1.w};
    const float sv0[4] = {s.vq0.x, s.vq0.y, s.vq0.z, s.vq0.w};
    const float sv1[4] = {s.vq1.x, s.vq1.y, s.vq1.z, s.vq1.w};
    uint32_t xk[4], xv[4];
    #pragma unroll
    for (int j = 0; j < 4; ++j) {
        const float fk0 = feat(sk0[j]);
        const float fk1 = feat(sk1[j]);
        zacc[j] += fk0 + fk1;
        xk[j] = cvt_pk_bf16(fk0, fk1);
        xv[j] = cvt_pk_bf16(sv0[j], sv1[j]);
    }
    xpose4(xk[0], xk[1], xk[2], xk[3]);
    xpose4(xv[0], xv[1], xv[2], xv[3]);
    const int row = c0 + q;   // c0 = 4a
    *reinterpret_cast<uint4*>(&Kbuf[row][woct * 8]) = make_uint4(xk[0], xk[1], xk[2], xk[3]);
    *reinterpret_cast<uint4*>(&Vbuf[row][woct * 8]) = make_uint4(xv[0], xv[1], xv[2], xv[3]);
}

__device__ __forceinline__ void mfma_step(const __hip_bfloat16 (*Kbuf)[PAD],
                                          const __hip_bfloat16 (*Vbuf)[PAD],
                                          f32x4& acc00, f32x4& acc01,
                                          f32x4& acc10, f32x4& acc11,
                                          int wm, int wd, int g, int lr) {
    const bf16x8 fa0 = *reinterpret_cast<const bf16x8*>(&Vbuf[wm + lr][g * 8]);
    const bf16x8 fa1 = *reinterpret_cast<const bf16x8*>(&Vbuf[wm + 16 + lr][g * 8]);
    const bf16x8 fb0 = *reinterpret_cast<const bf16x8*>(&Kbuf[wd + lr][g * 8]);
    const bf16x8 fb1 = *reinterpret_cast<const bf16x8*>(&Kbuf[wd + 16 + lr][g * 8]);
    acc00 = __builtin_amdgcn_mfma_f32_16x16x32_bf16(fa0, fb0, acc00, 0, 0, 0);
    acc01 = __builtin_amdgcn_mfma_f32_16x16x32_bf16(fa0, fb1, acc01, 0, 0, 0);
    acc10 = __builtin_amdgcn_mfma_f32_16x16x32_bf16(fa1, fb0, acc10, 0, 0, 0);
    acc11 = __builtin_amdgcn_mfma_f32_16x16x32_bf16(fa1, fb1, acc11, 0, 0, 0);
}

// INSTRUMENTATION ROUND: rcla_partial repeats its body `reps` times
// (accumulators re-zeroed per rep; outputs written once -> identical
// results) so its dispatch exceeds the ~155us harness fills and appears
// in the rocprof top-5 with real counters.
__global__ __launch_bounds__(256)
void rcla_partial(const float* __restrict__ key,
                  const float* __restrict__ value,
                  const int* __restrict__ mask,
                  float* __restrict__ ws, int C, int reps) {
    const int blk = blockIdx.x;
    const int c  = blk % C;
    const int bn = blk / C;
    const int b  = bn >> 4;   // N = 16
    const int n  = bn & 15;
    const int t  = threadIdx.x;

    const int a  = t & 15;
    const int p  = t >> 4;
    const int c0 = a << 2;
    const int sl = p << 1;
    const int q  = p & 3;
    const int woct = p >> 2;

    const int lane = t & 63;
    const int w    = t >> 6;
    const int wm   = (w >> 1) << 5;
    const int wd   = (w & 1) << 5;
    const int g    = lane >> 4;
    const int lr   = lane & 15;

    __shared__ __align__(16) __hip_bfloat16 Kl[2][DD][PAD];
    __shared__ __align__(16) __hip_bfloat16 Vl[2][MM][PAD];

    const int steps   = SS / C;
    const int nt      = steps / TS;
    const int s_begin = c * steps;

    const float* kb = key   + (((size_t)b * SS) * NN + n) * DD + (size_t)s_begin * (NN * DD);
    const float* vb = value + (((size_t)b * SS) * NN + n) * MM + (size_t)s_begin * (NN * MM);
    const int*   mb = mask  + (size_t)b * SS + s_begin;

    uint32_t bits = 0;
    for (int i = 0; i < nt; ++i) {
        bits |= (uint32_t)(mb[i * TS + sl]     != 0) << (2 * i);
        bits |= (uint32_t)(mb[i * TS + sl + 1] != 0) << (2 * i + 1);
    }

    f32x4 acc00 = {}, acc01 = {}, acc10 = {}, acc11 = {};
    float zacc[4] = {0.f, 0.f, 0.f, 0.f};

    for (int rep = 0; rep < reps; ++rep) {
        asm volatile("" ::: "memory");   // force re-execution of loads per rep
        acc00 = f32x4{}; acc01 = f32x4{}; acc10 = f32x4{}; acc11 = f32x4{};
        zacc[0] = zacc[1] = zacc[2] = zacc[3] = 0.f;

        Slot sA, sB;
        load_tile(sA, 0, bits, kb, vb, sl, c0);
        load_tile(sB, 1, bits, kb, vb, sl, c0);

        for (int ti = 0; ti < nt; ti += 2) {
            stage_tile(sA, zacc, Kl[0], Vl[0], c0, q, woct);
            if (ti + 2 < nt) load_tile(sA, ti + 2, bits, kb, vb, sl, c0);
            SYNCW();
            mfma_step(Kl[0], Vl[0], acc00, acc01, acc10, acc11, wm, wd, g, lr);

            stage_tile(sB, zacc, Kl[1], Vl[1], c0, q, woct);
            if (ti + 3 < nt) load_tile(sB, ti + 3, bits, kb, vb, sl, c0);
            SYNCW();
            mfma_step(Kl[1], Vl[1], acc00, acc01, acc10, acc11, wm, wd, g, lr);
        }
        SYNCW();   // fence between rep r's last MFMA reads and rep r+1's stage writes
    }

    float* out = ws + ((size_t)bn * C + c) * 4160;
    #pragma unroll
    for (int r = 0; r < 4; ++r) {
        out[(wm + g * 4 + r) * DD + wd + lr]           = acc00[r];
        out[(wm + g * 4 + r) * DD + wd + 16 + lr]      = acc01[r];
        out[(wm + 16 + g * 4 + r) * DD + wd + lr]      = acc10[r];
        out[(wm + 16 + g * 4 + r) * DD + wd + 16 + lr] = acc11[r];
    }

    __syncthreads();
    float* Zf = reinterpret_cast<float*>(&Kl[0][0][0]);
    *reinterpret_cast<float4*>(&Zf[p * DD + c0]) =
        make_float4(zacc[0], zacc[1], zacc[2], zacc[3]);
    __syncthreads();
    if (t < DD) {
        float z = 0.f;
        #pragma unroll
        for (int qq = 0; qq < 16; ++qq) z += Zf[qq * DD + t];
        out[4096 + t] = z;
    }
}

// DECOY (instrumentation): identical grid + identical predicated K/V
// access pattern, but NO LDS/MFMA/barriers — pure load+sum. Its per-pass
// time is the measured memory floor of this access pattern.
__global__ __launch_bounds__(256)
void rcla_stream(const float* __restrict__ key,
                 const float* __restrict__ value,
                 const int* __restrict__ mask,
                 float* __restrict__ decoy, int C, int reps) {
    const int blk = blockIdx.x;
    const int c  = blk % C;
    const int bn = blk / C;
    const int b  = bn >> 4;
    const int n  = bn & 15;
    const int t  = threadIdx.x;
    const int a  = t & 15;
    const int p  = t >> 4;
    const int c0 = a << 2;
    const int sl = p << 1;

    const int steps   = SS / C;
    const int nt      = steps / TS;
    const int s_begin = c * steps;

    const float* kb = key   + (((size_t)b * SS) * NN + n) * DD + (size_t)s_begin * (NN * DD);
    const float* vb = value + (((size_t)b * SS) * NN + n) * MM + (size_t)s_begin * (NN * MM);
    const int*   mb = mask  + (size_t)b * SS + s_begin;

    uint32_t bits = 0;
    for (int i = 0; i < nt; ++i) {
        bits |= (uint32_t)(mb[i * TS + sl]     != 0) << (2 * i);
        bits |= (uint32_t)(mb[i * TS + sl + 1] != 0) << (2 * i + 1);
    }

    float acc = 0.f;
    for (int rep = 0; rep < reps; ++rep) {
        asm volatile("" ::: "memory");   // prevent load hoisting across reps
        for (int ti = 0; ti < nt; ++ti) {
            Slot s;
            load_tile(s, ti, bits, kb, vb, sl, c0);
            acc += s.kq0.x + s.kq0.y + s.kq0.z + s.kq0.w
                 + s.kq1.x + s.kq1.y + s.kq1.z + s.kq1.w
                 + s.vq0.x + s.vq0.y + s.vq0.z + s.vq0.w
                 + s.vq1.x + s.vq1.y + s.vq1.z + s.vq1.w;
        }
    }
    decoy[(size_t)blk * 256 + t] = acc;
}

// One block per (bn, m-quarter): reduce C partials, emit Sst/Z, then QZ, V.
__global__ __launch_bounds__(256)
void rcla_final(const float* __restrict__ query,
                const float* __restrict__ ws, int C,
                float* __restrict__ outV, float* __restrict__ outS,
                float* __restrict__ outZ) {
    const int q   = blockIdx.x & 3;
    const int bn  = blockIdx.x >> 2;
    const int t   = threadIdx.x;
    const int d0  = (t & 15) << 2;
    const int mr  = (q << 4) + (t >> 4);
    const float* p0 = ws + (size_t)bn * C * 4160;

    float sst[4] = {0.f, 0.f, 0.f, 0.f};
    float z[4]   = {0.f, 0.f, 0.f, 0.f};

    for (int c = 0; c < C; ++c) {
        const float* p = p0 + (size_t)c * 4160;
        const float4 v = *reinterpret_cast<const float4*>(p + mr * DD + d0);
        sst[0] += v.x; sst[1] += v.y; sst[2] += v.z; sst[3] += v.w;
        const float4 zv = *reinterpret_cast<const float4*>(p + 4096 + d0);
        z[0] += zv.x; z[1] += zv.y; z[2] += zv.z; z[3] += zv.w;
    }

    *reinterpret_cast<float4*>(outS + (size_t)bn * 4096 + mr * DD + d0) =
        make_float4(sst[0], sst[1], sst[2], sst[3]);
    if (q == 0 && t < 16) {
        *reinterpret_cast<float4*>(outZ + (size_t)bn * DD + d0) =
            make_float4(z[0], z[1], z[2], z[3]);
    }

    float qf[4];
    #pragma unroll
    for (int j = 0; j < 4; ++j) qf[j] = feat(query[(size_t)bn * DD + d0 + j]);

    float pd = qf[0]*z[0] + qf[1]*z[1] + qf[2]*z[2] + qf[3]*z[3];
    float pv = qf[0]*sst[0] + qf[1]*sst[1] + qf[2]*sst[2] + qf[3]*sst[3];
    #pragma unroll
    for (int off = 1; off < 16; off <<= 1) {
        pd += __shfl_xor(pd, off);
        pv += __shfl_xor(pv, off);
    }
    if ((t & 15) == 0) {
        const float qz = 1.0f / (pd + 1e-6f);
        outV[(size_t)bn * MM + mr] = qz * pv;
    }
}

extern "C" void kernel_launch(void* const* d_in, const int* in_sizes, int n_in,
                              void* d_out, int out_size, void* d_ws, size_t ws_size,
                              hipStream_t stream) {
    const float* query = (const float*)d_in[0];
    const float* key   = (const float*)d_in[1];
    const float* value = (const float*)d_in[2];
    const int*   mask  = (const int*)d_in[3];

    float* out  = (float*)d_out;
    float* outV = out;                         // [B,N,M]   8192
    float* outS = out + BB * NN * MM;          // [B,N,M,D] 524288
    float* outZ = outS + BB * NN * MM * DD;    // [B,N,D]   8192
    float* ws   = (float*)d_ws;

    int C = 16;   // 2048 blocks -> 8 blocks/CU
    while (C > 8 && (size_t)BB * NN * C * 4160 * sizeof(float) > ws_size) C >>= 1;

    // decoy region safely past the real partials (~34 MB)
    float* decoy = ws + (size_t)BB * NN * C * 4160 + 1024;

    rcla_partial<<<dim3(BB * NN * C), dim3(256), 0, stream>>>(key, value, mask, ws, C, 4);
    rcla_stream <<<dim3(BB * NN * C), dim3(256), 0, stream>>>(key, value, mask, decoy, C, 8);
    rcla_final  <<<dim3(BB * NN * 4), dim3(256), 0, stream>>>(query, ws, C, outV, outS, outZ);
}

// Round 11
// 65.285 us; speedup vs baseline: 7.1689x; 7.1689x over previous
//
#include <hip/hip_runtime.h>
#include <hip/hip_bf16.h>
#include <stdint.h>
#include <math.h>

#define BB 8
#define SS 8192
#define NN 16
#define DD 64
#define MM 64
#define TS 32    // s-rows per LDS tile
#define PAD 40   // row stride (bf16): 80 B; b128 writes/reads both hit all 32 banks

// per-(bn,c) partial record: 4096 bf16 Sst (8192 B) + 64 f32 Z (256 B)
#define PREC_BYTES 8448

typedef __attribute__((ext_vector_type(8))) short bf16x8;
typedef __attribute__((ext_vector_type(4))) float f32x4;

__device__ __forceinline__ float feat(float x) {
    // elu(x) + 1 == x+1 (x>0), exp(x) (x<=0); feat(-inf) = 0 (masked rows)
    return x > 0.0f ? (x + 1.0f) : __expf(x);
}

__device__ __forceinline__ uint32_t cvt_pk_bf16(float lo, float hi) {
    uint32_t r;
    asm("v_cvt_pk_bf16_f32 %0, %1, %2" : "=v"(r) : "v"(lo), "v"(hi));
    return r;
}

// 4x4 cross-lane u32 transpose on the VALU pipe (not LDS).
__device__ __forceinline__ void xpose4(uint32_t& x0, uint32_t& x1,
                                       uint32_t& x2, uint32_t& x3) {
    asm("v_permlane32_swap_b32 %0, %1" : "+v"(x0), "+v"(x2));
    asm("v_permlane32_swap_b32 %0, %1" : "+v"(x1), "+v"(x3));
    asm("v_permlane16_swap_b32 %0, %1" : "+v"(x0), "+v"(x1));
    asm("v_permlane16_swap_b32 %0, %1" : "+v"(x2), "+v"(x3));
}

// Raw barrier (no vmcnt drain): global loads stay in flight across it.
#define SYNCW()                                        \
    do {                                               \
        __builtin_amdgcn_sched_barrier(0);             \
        asm volatile("s_waitcnt lgkmcnt(0)");          \
        __builtin_amdgcn_s_barrier();                  \
        __builtin_amdgcn_sched_barrier(0);             \
    } while (0)

struct Slot {
    float4 kq0, kq1, vq0, vq1;
};

__device__ __forceinline__ void load_tile(Slot& s, int ti, uint32_t bits,
                                          const float* kb, const float* vb,
                                          int sl, int c0) {
    const bool lv0 = !((bits >> (2 * ti)) & 1);
    const bool lv1 = !((bits >> (2 * ti + 1)) & 1);
    // masked K rows preset to -inf -> feat() yields 0 with no predication;
    // masked V rows stay 0 (K=0 zeroes their MFMA contribution anyway).
    const float ninf = -INFINITY;
    s.kq0 = make_float4(ninf, ninf, ninf, ninf);
    s.kq1 = make_float4(ninf, ninf, ninf, ninf);
    s.vq0 = make_float4(0.f, 0.f, 0.f, 0.f);
    s.vq1 = make_float4(0.f, 0.f, 0.f, 0.f);
    const size_t s0 = (size_t)(ti * TS + sl);
    if (lv0) {
        s.kq0 = *reinterpret_cast<const float4*>(kb + s0 * (NN * DD) + c0);
        s.vq0 = *reinterpret_cast<const float4*>(vb + s0 * (NN * MM) + c0);
    }
    if (lv1) {
        s.kq1 = *reinterpret_cast<const float4*>(kb + (s0 + 1) * (NN * DD) + c0);
        s.vq1 = *reinterpret_cast<const float4*>(vb + (s0 + 1) * (NN * MM) + c0);
    }
}

__device__ __forceinline__ void stage_tile(const Slot& s, float* zacc,
                                           __hip_bfloat16 (*Kbuf)[PAD],
                                           __hip_bfloat16 (*Vbuf)[PAD],
                                           int c0, int q, int woct) {
    const float sk0[4] = {s.kq0.x, s.kq0.y, s.kq0.z, s.kq0.w};
    const float sk1[4] = {s.kq1.x, s.kq1.y, s.kq1.z, s.kq1.w};
    const float sv0[4] = {s.vq0.x, s.vq0.y, s.vq0.z, s.vq0.w};
    const float sv1[4] = {s.vq1.x, s.vq1.y, s.vq1.z, s.vq1.w};
    uint32_t xk[4], xv[4];
    #pragma unroll
    for (int j = 0; j < 4; ++j) {
        const float fk0 = feat(sk0[j]);
        const float fk1 = feat(sk1[j]);
        zacc[j] += fk0 + fk1;
        xk[j] = cvt_pk_bf16(fk0, fk1);
        xv[j] = cvt_pk_bf16(sv0[j], sv1[j]);
    }
    xpose4(xk[0], xk[1], xk[2], xk[3]);
    xpose4(xv[0], xv[1], xv[2], xv[3]);
    const int row = c0 + q;   // c0 = 4a
    *reinterpret_cast<uint4*>(&Kbuf[row][woct * 8]) = make_uint4(xk[0], xk[1], xk[2], xk[3]);
    *reinterpret_cast<uint4*>(&Vbuf[row][woct * 8]) = make_uint4(xv[0], xv[1], xv[2], xv[3]);
}

__device__ __forceinline__ void mfma_step(const __hip_bfloat16 (*Kbuf)[PAD],
                                          const __hip_bfloat16 (*Vbuf)[PAD],
                                          f32x4& acc00, f32x4& acc01,
                                          f32x4& acc10, f32x4& acc11,
                                          int wm, int wd, int g, int lr) {
    const bf16x8 fa0 = *reinterpret_cast<const bf16x8*>(&Vbuf[wm + lr][g * 8]);
    const bf16x8 fa1 = *reinterpret_cast<const bf16x8*>(&Vbuf[wm + 16 + lr][g * 8]);
    const bf16x8 fb0 = *reinterpret_cast<const bf16x8*>(&Kbuf[wd + lr][g * 8]);
    const bf16x8 fb1 = *reinterpret_cast<const bf16x8*>(&Kbuf[wd + 16 + lr][g * 8]);
    acc00 = __builtin_amdgcn_mfma_f32_16x16x32_bf16(fa0, fb0, acc00, 0, 0, 0);
    acc01 = __builtin_amdgcn_mfma_f32_16x16x32_bf16(fa0, fb1, acc01, 0, 0, 0);
    acc10 = __builtin_amdgcn_mfma_f32_16x16x32_bf16(fa1, fb0, acc10, 0, 0, 0);
    acc11 = __builtin_amdgcn_mfma_f32_16x16x32_bf16(fa1, fb1, acc11, 0, 0, 0);
}

// One block per (bn, chunk). 256 threads = 4 waves; wave w owns the 32x32
// output quadrant (wm, wd) of Sst[64][64] and stages s-octet w of each tile.
// Memory-bound at the cold-HBM floor of the mask-scattered read pattern
// (instrumentation r10: partial/pass ~= pure-load decoy/pass). Partials are
// written as bf16 (Sst) + f32 (Z) to halve ws traffic.
__global__ __launch_bounds__(256)
void rcla_partial(const float* __restrict__ key,
                  const float* __restrict__ value,
                  const int* __restrict__ mask,
                  char* __restrict__ ws, int C) {
    const int blk = blockIdx.x;
    const int c  = blk % C;
    const int bn = blk / C;
    const int b  = bn >> 4;   // N = 16
    const int n  = bn & 15;
    const int t  = threadIdx.x;

    const int a  = t & 15;
    const int p  = t >> 4;
    const int c0 = a << 2;
    const int sl = p << 1;
    const int q  = p & 3;
    const int woct = p >> 2;

    const int lane = t & 63;
    const int w    = t >> 6;
    const int wm   = (w >> 1) << 5;
    const int wd   = (w & 1) << 5;
    const int g    = lane >> 4;
    const int lr   = lane & 15;

    __shared__ __align__(16) __hip_bfloat16 Kl[2][DD][PAD];
    __shared__ __align__(16) __hip_bfloat16 Vl[2][MM][PAD];

    const int steps   = SS / C;      // 512 at C=16
    const int nt      = steps / TS;  // 16
    const int s_begin = c * steps;

    const float* kb = key   + (((size_t)b * SS) * NN + n) * DD + (size_t)s_begin * (NN * DD);
    const float* vb = value + (((size_t)b * SS) * NN + n) * MM + (size_t)s_begin * (NN * MM);
    const int*   mb = mask  + (size_t)b * SS + s_begin;

    uint32_t bits = 0;
    for (int i = 0; i < nt; ++i) {
        bits |= (uint32_t)(mb[i * TS + sl]     != 0) << (2 * i);
        bits |= (uint32_t)(mb[i * TS + sl + 1] != 0) << (2 * i + 1);
    }

    f32x4 acc00 = {}, acc01 = {}, acc10 = {}, acc11 = {};
    float zacc[4] = {0.f, 0.f, 0.f, 0.f};

    Slot sA, sB;
    load_tile(sA, 0, bits, kb, vb, sl, c0);
    load_tile(sB, 1, bits, kb, vb, sl, c0);

    for (int ti = 0; ti < nt; ti += 2) {
        stage_tile(sA, zacc, Kl[0], Vl[0], c0, q, woct);
        if (ti + 2 < nt) load_tile(sA, ti + 2, bits, kb, vb, sl, c0);
        SYNCW();
        mfma_step(Kl[0], Vl[0], acc00, acc01, acc10, acc11, wm, wd, g, lr);

        stage_tile(sB, zacc, Kl[1], Vl[1], c0, q, woct);
        if (ti + 3 < nt) load_tile(sB, ti + 3, bits, kb, vb, sl, c0);
        SYNCW();
        mfma_step(Kl[1], Vl[1], acc00, acc01, acc10, acc11, wm, wd, g, lr);
    }

    // partial record: bf16 Sst[64][64] then f32 Z[64]
    char* rec = ws + ((size_t)bn * C + c) * PREC_BYTES;
    __hip_bfloat16* outS16 = reinterpret_cast<__hip_bfloat16*>(rec);
    float*          outZ32 = reinterpret_cast<float*>(rec + 8192);

    // C/D layout: col = lane&15, row = (lane>>4)*4 + reg
    #pragma unroll
    for (int r = 0; r < 4; ++r) {
        outS16[(wm + g * 4 + r) * DD + wd + lr]           = __float2bfloat16(acc00[r]);
        outS16[(wm + g * 4 + r) * DD + wd + 16 + lr]      = __float2bfloat16(acc01[r]);
        outS16[(wm + 16 + g * 4 + r) * DD + wd + lr]      = __float2bfloat16(acc10[r]);
        outS16[(wm + 16 + g * 4 + r) * DD + wd + 16 + lr] = __float2bfloat16(acc11[r]);
    }

    // Z reduction: reuse Kl[0] as float scratch (fenced by __syncthreads).
    __syncthreads();
    float* Zf = reinterpret_cast<float*>(&Kl[0][0][0]);   // [16][64] floats
    *reinterpret_cast<float4*>(&Zf[p * DD + c0]) =
        make_float4(zacc[0], zacc[1], zacc[2], zacc[3]);
    __syncthreads();
    if (t < DD) {
        float z = 0.f;
        #pragma unroll
        for (int qq = 0; qq < 16; ++qq) z += Zf[qq * DD + t];
        outZ32[t] = z;
    }
}

// One block per (bn, m-quarter): reduce C bf16 partials for 16 m-rows, emit
// Sst (and Z from quarter 0), then QZ and V.
__global__ __launch_bounds__(256)
void rcla_final(const float* __restrict__ query,
                const char* __restrict__ ws, int C,
                float* __restrict__ outV, float* __restrict__ outS,
                float* __restrict__ outZ) {
    const int q   = blockIdx.x & 3;
    const int bn  = blockIdx.x >> 2;
    const int t   = threadIdx.x;
    const int d0  = (t & 15) << 2;
    const int mr  = (q << 4) + (t >> 4);
    const char* p0 = ws + (size_t)bn * C * PREC_BYTES;

    float sst[4] = {0.f, 0.f, 0.f, 0.f};
    float z[4]   = {0.f, 0.f, 0.f, 0.f};

    for (int c = 0; c < C; ++c) {
        const char* rec = p0 + (size_t)c * PREC_BYTES;
        const __hip_bfloat16* ps =
            reinterpret_cast<const __hip_bfloat16*>(rec) + mr * DD + d0;
        const ushort4 v4 = *reinterpret_cast<const ushort4*>(ps);   // 8B aligned
        sst[0] += __bfloat162float(*reinterpret_cast<const __hip_bfloat16*>(&v4.x));
        sst[1] += __bfloat162float(*reinterpret_cast<const __hip_bfloat16*>(&v4.y));
        sst[2] += __bfloat162float(*reinterpret_cast<const __hip_bfloat16*>(&v4.z));
        sst[3] += __bfloat162float(*reinterpret_cast<const __hip_bfloat16*>(&v4.w));
        const float4 zv =
            *reinterpret_cast<const float4*>(rec + 8192 + (size_t)d0 * 4);
        z[0] += zv.x; z[1] += zv.y; z[2] += zv.z; z[3] += zv.w;
    }

    *reinterpret_cast<float4*>(outS + (size_t)bn * 4096 + mr * DD + d0) =
        make_float4(sst[0], sst[1], sst[2], sst[3]);
    if (q == 0 && t < 16) {
        *reinterpret_cast<float4*>(outZ + (size_t)bn * DD + d0) =
            make_float4(z[0], z[1], z[2], z[3]);
    }

    float qf[4];
    #pragma unroll
    for (int j = 0; j < 4; ++j) qf[j] = feat(query[(size_t)bn * DD + d0 + j]);

    float pd = qf[0]*z[0] + qf[1]*z[1] + qf[2]*z[2] + qf[3]*z[3];
    float pv = qf[0]*sst[0] + qf[1]*sst[1] + qf[2]*sst[2] + qf[3]*sst[3];
    #pragma unroll
    for (int off = 1; off < 16; off <<= 1) {
        pd += __shfl_xor(pd, off);
        pv += __shfl_xor(pv, off);
    }
    if ((t & 15) == 0) {
        const float qz = 1.0f / (pd + 1e-6f);
        outV[(size_t)bn * MM + mr] = qz * pv;
    }
}

extern "C" void kernel_launch(void* const* d_in, const int* in_sizes, int n_in,
                              void* d_out, int out_size, void* d_ws, size_t ws_size,
                              hipStream_t stream) {
    const float* query = (const float*)d_in[0];
    const float* key   = (const float*)d_in[1];
    const float* value = (const float*)d_in[2];
    const int*   mask  = (const int*)d_in[3];

    float* out  = (float*)d_out;
    float* outV = out;                         // [B,N,M]   8192
    float* outS = out + BB * NN * MM;          // [B,N,M,D] 524288
    float* outZ = outS + BB * NN * MM * DD;    // [B,N,D]   8192
    char*  ws   = (char*)d_ws;

    int C = 16;   // 2048 blocks -> 8 blocks/CU
    while (C > 8 && (size_t)BB * NN * C * PREC_BYTES > ws_size) C >>= 1;

    rcla_partial<<<dim3(BB * NN * C), dim3(256), 0, stream>>>(key, value, mask, ws, C);
    rcla_final  <<<dim3(BB * NN * 4), dim3(256), 0, stream>>>(query, ws, C, outV, outS, outZ);
}